// Round 9
// baseline (47.238 us; speedup 1.0000x reference)
//
#include <hip/hip_runtime.h>
#include <hip/hip_bf16.h>
#include <math.h>

#define B_ROWS 4096
#define N_ROWS 8192
#define D_DIM  128
// (1/T) * log2(e) = 2 * 1.4426950408889634
#define SCALE_LOG2 2.8853900817779268f
// sqrt(SCALE_LOG2): folded into row normalization so MFMA output is already
// in log2 domain
#define PRESCALE 1.6986436f
// ln2/4: converts the 4x-duplicated group-dot back to the label logit 2*cos
#define LN2_OVER_4 0.17328679513998632f

#define RSPLIT 64                      // 128-row blocks
#define CSPLIT 64                      // 128-col blocks

typedef __bf16 bf16x8 __attribute__((ext_vector_type(8)));
typedef __bf16 bf16x2 __attribute__((ext_vector_type(2)));
typedef float  f32x4  __attribute__((ext_vector_type(4)));

#if __has_builtin(__builtin_amdgcn_exp2f)
#define EXP2F(x) __builtin_amdgcn_exp2f(x)
#else
#define EXP2F(x) exp2f(x)
#endif

// Packed fragment-major layout for 16x16x32 MFMA (16B chunk units):
//   chunk(p, kk, l) = zn[p*16 + (l&15)][ kk*32 + (l>>4)*8 .. +8 ]   (8 bf16)
//   addr16B = p*256 + kk*64 + l      (p = 16-row panel, kk = K/32 group)
// one wave fragment load = 64 consecutive 16B chunks = 1KB coalesced.

// ---------- K1: normalize rows of concat(z_i, z_j) -> packed bf16 ----------
__global__ __launch_bounds__(256) void k_normalize(const float* __restrict__ zi,
                                                   const float* __restrict__ zj,
                                                   __bf16* __restrict__ pack) {
    const int wid  = threadIdx.x >> 6;
    const int lane = threadIdx.x & 63;
    const int row  = blockIdx.x * 4 + wid;
    const float* src = (row < B_ROWS) ? (zi + (size_t)row * D_DIM)
                                      : (zj + (size_t)(row - B_ROWS) * D_DIM);
    float2 v = ((const float2*)src)[lane];
    float ss = v.x * v.x + v.y * v.y;
    #pragma unroll
    for (int off = 1; off < 64; off <<= 1) ss += __shfl_xor(ss, off, 64);
    float inv = PRESCALE / fmaxf(sqrtf(ss), 1e-8f);
    bf16x2 o;
    o[0] = (__bf16)(v.x * inv);
    o[1] = (__bf16)(v.y * inv);
    // elems e = 2*lane, 2*lane+1: kk = lane>>4, sub = (lane>>2)&3, m2 = lane&3
    const int chunk = ((row >> 4) << 8) + ((lane >> 4) << 6) +
                      (((lane >> 2) & 3) << 4) + (row & 15);
    ((bf16x2*)pack)[chunk * 4 + (lane & 3)] = o;
}

// ---------- K2: upper-triangle NT-GEMM, register-light 16x16x32 ----------
// block = 4 waves, 128x128 output tile, grid 64x64 upper-triangle (cs>=rb).
// Wave w owns two 16-row strips (w*16 and 64+w*16) x 128 cols = 8 col-tiles.
// 16x16x32 MFMA: acc = 4 AGPR (not 16), frags 4 VGPR -> total ~90 regs ->
// 4 waves/SIMD resident (2-3x the 32x32 variants), no LDS B-staging (L2/L3
// serves the 2MB pack; R6/R7 proved staging is not the lever). Short dep
// chains: {4 loads -> 8 MFMA -> 8 exp2} x 8 independent col-tiles.
// Symmetry: off-diag blocks also produce col-sums (slot rb of col rows).
__global__ __launch_bounds__(256, 4) void k_gemm_expsum(const __bf16* __restrict__ pack,
                                                        float* __restrict__ partials) {
    const int rb = blockIdx.x;     // 0..63 row-block (128 rows)
    const int cs = blockIdx.y;     // 0..63 col-block (128 cols)
    if (cs < rb) return;           // lower triangle: covered by symmetry

    const int wid  = threadIdx.x >> 6;
    const int lane = threadIdx.x & 63;
    const int lq   = lane >> 4;    // row-group (0..3)
    const int lc   = lane & 15;    // col within tile

    __shared__ float cls[4][128];  // per-wave column sums (2 KB)

    const bf16x8* pk = (const bf16x8*)pack;   // 16B chunk units
    const int row0 = rb * 128 + wid * 16;     // strip0; strip1 = +64

    // A fragments for both strips (coalesced 1KB loads)
    const int pA0 = rb * 8 + wid;             // 16-row panel index
    bf16x8 a0[4], a1[4];
    #pragma unroll
    for (int kk = 0; kk < 4; ++kk) {
        a0[kk] = pk[(size_t)pA0 * 256 + kk * 64 + lane];
        a1[kk] = pk[(size_t)(pA0 + 4) * 256 + kk * 64 + lane];
    }

    float sums0[4] = {0.f, 0.f, 0.f, 0.f};
    float sums1[4] = {0.f, 0.f, 0.f, 0.f};
    float csum[8];

    #pragma unroll
    for (int t = 0; t < 8; ++t) {
        const size_t pb = (size_t)(cs * 8 + t) * 256;
        bf16x8 b[4];
        #pragma unroll
        for (int kk = 0; kk < 4; ++kk)
            b[kk] = pk[pb + kk * 64 + lane];
        f32x4 acc0 = {};
        f32x4 acc1 = {};
        #pragma unroll
        for (int kk = 0; kk < 4; ++kk) {
            acc0 = __builtin_amdgcn_mfma_f32_16x16x32_bf16(a0[kk], b[kk], acc0, 0, 0, 0);
            acc1 = __builtin_amdgcn_mfma_f32_16x16x32_bf16(a1[kk], b[kk], acc1, 0, 0, 0);
        }
        // rows pre-scaled: acc = logit*log2e, bounded |.|<=2.89 -> plain exp2
        float cacc = 0.0f;
        #pragma unroll
        for (int r = 0; r < 4; ++r) {
            float e0 = EXP2F(acc0[r]);
            float e1 = EXP2F(acc1[r]);
            sums0[r] += e0;
            sums1[r] += e1;
            cacc += e0 + e1;     // this lane's column (t*16+lc) contribution
        }
        csum[t] = cacc;          // static index (unrolled)
    }

    // row-path: C layout col=lane&15, row=(lane>>4)*4+r. Reduce across the
    // 16 col-lanes; lane lc==0 of each row-group writes slot cs.
    #pragma unroll
    for (int r = 0; r < 4; ++r) {
        float s0 = sums0[r];
        float s1 = sums1[r];
        #pragma unroll
        for (int off = 1; off < 16; off <<= 1) {
            s0 += __shfl_xor(s0, off, 64);
            s1 += __shfl_xor(s1, off, 64);
        }
        if (lc == 0) {
            const int rr = lq * 4 + r;
            partials[(size_t)(row0 + rr) * CSPLIT + cs]      = s0;
            partials[(size_t)(row0 + 64 + rr) * CSPLIT + cs] = s1;
        }
    }

    // col-path: reduce across the 4 row-groups (lanes lc, lc+16, lc+32, lc+48),
    // combine the block's 4 waves via LDS, write slot rb of the column rows.
    #pragma unroll
    for (int t = 0; t < 8; ++t) {
        float v = csum[t];
        v += __shfl_xor(v, 16, 64);
        v += __shfl_xor(v, 32, 64);
        csum[t] = v;
    }
    if (lane < 16) {
        #pragma unroll
        for (int t = 0; t < 8; ++t)
            cls[wid][t * 16 + lane] = csum[t];
    }
    __syncthreads();
    if (cs > rb && threadIdx.x < 128) {
        const int t = threadIdx.x;
        float v = cls[0][t] + cls[1][t] + cls[2][t] + cls[3][t];
        partials[(size_t)(cs * 128 + t) * CSPLIT + rb] = v;
    }
}

// ---------- K3: merge partials + label logit + nll -> loss ----------
// grid 256 x 4 waves; each wave owns 8 rows. Per row: coalesced 256B partial
// read (64 lanes = 64 slots) + 4x-duplicated 16-group label dot.
__global__ __launch_bounds__(256) void k_finalize(const __bf16* __restrict__ pack,
                                                  const float* __restrict__ partials,
                                                  float* __restrict__ out) {
    const int wid  = threadIdx.x >> 6;
    const int lane = threadIdx.x & 63;
    const int rowbase = blockIdx.x * 32 + wid * 8;
    const bf16x8* pk = (const bf16x8*)pack;

    // group g = lane&15 covers elems g*8..g*8+7: kk=g>>2, sub=g&3
    const int g = lane & 15;
    const int goff = ((g >> 2) << 6) + ((g & 3) << 4);

    float accv = 0.0f;
    #pragma unroll
    for (int it = 0; it < 8; ++it) {
        const int r = rowbase + it;
        const int c = (r < B_ROWS) ? r : r - B_ROWS;   // label column
        float p = partials[(size_t)r * CSPLIT + lane];
        bf16x8 av = pk[(size_t)(r >> 4) * 256 + goff + (r & 15)];
        bf16x8 bv = pk[(size_t)(c >> 4) * 256 + goff + (c & 15)];
        float d = 0.0f;
        #pragma unroll
        for (int e = 0; e < 8; ++e) d += (float)av[e] * (float)bv[e];
        // 64-lane reduce: p -> row exp-sum; d -> 4 * SCALE_LOG2 * cos(r,c)
        #pragma unroll
        for (int off = 1; off < 64; off <<= 1) {
            d += __shfl_xor(d, off, 64);
            p += __shfl_xor(p, off, 64);
        }
        if (lane == 0) {
            // nll = ln(sum) - 2*cos = logf(p) - d * ln2/4
            accv += logf(p) - d * LN2_OVER_4;
        }
    }
    __shared__ float ls[4];
    if (lane == 0) ls[wid] = accv;
    __syncthreads();
    if (threadIdx.x == 0) {
        atomicAdd(out, (ls[0] + ls[1] + ls[2] + ls[3]) * (1.0f / (float)N_ROWS));
    }
}

extern "C" void kernel_launch(void* const* d_in, const int* in_sizes, int n_in,
                              void* d_out, int out_size, void* d_ws, size_t ws_size,
                              hipStream_t stream) {
    const float* zi = (const float*)d_in[0];
    const float* zj = (const float*)d_in[1];
    float* out = (float*)d_out;

    __bf16* pack     = (__bf16*)d_ws;                                      // 2 MB
    float*  partials = (float*)((char*)d_ws + (size_t)N_ROWS * D_DIM * 2); // 2 MB

    hipMemsetAsync(out, 0, sizeof(float), stream);
    k_normalize<<<dim3(N_ROWS / 4), dim3(256), 0, stream>>>(zi, zj, pack);
    k_gemm_expsum<<<dim3(RSPLIT, CSPLIT), dim3(256), 0, stream>>>(pack, partials);
    k_finalize<<<dim3(N_ROWS / 32), dim3(256), 0, stream>>>(pack, partials, out);
}